// Round 7
// baseline (145.703 us; speedup 1.0000x reference)
//
#include <hip/hip_runtime.h>
#include <hip/hip_bf16.h>
#include <math.h>

#define D 384
#define EPS 1e-8f

#define RPB 512            // rows per block: 8 waves x 64
#define CPS 512            // cols per split: 4 positions x 128
#define POS_W 128          // fold granularity
#define NPOS 4
#define NHALF 8            // NPOS * 2 half-K steps
#define HKB 6              // k32 steps per half (192 k)
#define HALF_BYTES 49152   // 24 kgran x 2048 B = 48 KB

typedef __bf16  bf16x8  __attribute__((ext_vector_type(8)));
typedef float   floatx4 __attribute__((ext_vector_type(4)));

// ---------------- kernel 1: rnorm + normalized bf16 cast + ws init ----------------
__global__ __launch_bounds__(256) void prep_kernel(const float* __restrict__ in,
                                                   float* __restrict__ rnorm,
                                                   __hip_bfloat16* __restrict__ xb,
                                                   unsigned long long* __restrict__ best,
                                                   float* __restrict__ out, int N) {
    int row = blockIdx.x * 4 + (threadIdx.x >> 6);   // one wave per row
    if (blockIdx.x == 0 && threadIdx.x == 0) out[0] = 0.f;   // d_out poisoned each call
    if (row >= N) return;
    int lane = threadIdx.x & 63;
    const float* p = in + (size_t)row * D;
    float v[6];
    float s = 0.f;
#pragma unroll
    for (int c = 0; c < 6; ++c) { v[c] = p[lane + 64 * c]; s += v[c] * v[c]; }
#pragma unroll
    for (int off = 32; off >= 1; off >>= 1) s += __shfl_xor(s, off, 64);
    float rn = 1.0f / fmaxf(sqrtf(s), EPS);
    if (lane == 0) { rnorm[row] = rn; best[row] = 0ull; }    // ws poisoned each call
    __hip_bfloat16* q = xb + (size_t)row * D;
#pragma unroll
    for (int c = 0; c < 6; ++c) q[lane + 64 * c] = __float2bfloat16(v[c] * rn);
}

// ---------------- kernel 2: row-ownership MFMA scan, pipelined B staging ----------------
// Block owns 512 rows (8 waves x 64), scans 512 cols as 4 positions of 128.
// B double-buffered in LDS at half-K (192 k) granularity: glds for step s+1
// issue right after the barrier entering step s -> the next barrier's vmcnt
// drain finds them landed (no fresh-load drain stall, unlike per-k barriers).
// LDS layout [kgran][col]x16B: conflict-free b128 frag reads + glds lane-order.
// A fragments direct global->VGPR with one-step prefetch. Running-argmax fold.
__global__ __launch_bounds__(512, 2) void maxdot_rows(const __hip_bfloat16* __restrict__ xb,
                                                      unsigned long long* __restrict__ best) {
    __shared__ char Bs[2 * HALF_BYTES];              // 96 KB -> 1 block/CU

    const int t    = threadIdx.x;
    const int lane = t & 63;
    const int wv   = t >> 6;                         // 0..7
    const int quad = lane >> 4, l16 = lane & 15;
    const int rb   = blockIdx.x >> 4;                // 16 row-blocks
    const int cs   = blockIdx.x & 15;                // 16 col-splits
    const int row0b = rb * RPB;
    const int col0s = cs * CPS;
    const int wrow0 = row0b + wv * 64;

    floatx4 acc[4][8];
#pragma unroll
    for (int mi = 0; mi < 4; ++mi)
#pragma unroll
        for (int ni = 0; ni < 8; ++ni) acc[mi][ni] = (floatx4){0.f, 0.f, 0.f, 0.f};

    float rv[16];
    int   ri[16];
#pragma unroll
    for (int i = 0; i < 16; ++i) { rv[i] = -3.0f; ri[i] = 0; }

    // ---- staging: wave wv covers granule-blocks gb = wv*6+i ----
    // gb -> kgran = gb>>1, chalf = gb&1; lane covers col chalf*64+lane.
    // LDS addr = kgran*2048 + chalf*1024 + lane*16 (uniform + lane*16).
    auto stage = [&](int buf, int s) {
        const int pos = s >> 1, h = s & 1;
        const int colbase = col0s + pos * POS_W;
#pragma unroll
        for (int i = 0; i < 6; ++i) {
            const int gb = wv * 6 + i;
            const int kgran = gb >> 1, chalf = gb & 1;
            const char* g = (const char*)xb + (size_t)(colbase + chalf * 64 + lane) * 768
                            + h * 384 + kgran * 16;
            char* l = Bs + buf * HALF_BYTES + kgran * 2048 + chalf * 1024 + lane * 16;
            __builtin_amdgcn_global_load_lds((const __attribute__((address_space(1))) void*)g,
                                             (__attribute__((address_space(3))) void*)l, 16, 0, 0);
        }
    };
    auto loadA = [&](int kidx, bf16x8* dst) {        // kidx = k32 index 0..11 (pos-invariant)
#pragma unroll
        for (int mi = 0; mi < 4; ++mi)
            dst[mi] = *(const bf16x8*)(xb + (size_t)(wrow0 + mi * 16 + l16) * D + kidx * 32 + quad * 8);
    };

    stage(0, 0);
    bf16x8 af[4];
    loadA(0, af);

    int buf = 0;
    for (int s = 0; s < NHALF; ++s) {
        __syncthreads();                             // stage(s) landed (issued a full step ago)
        if (s + 1 < NHALF) stage(buf ^ 1, s + 1);    // drained only at the NEXT barrier
        const char* bb = Bs + buf * HALF_BYTES;
        const int h = s & 1;

#pragma unroll
        for (int kb = 0; kb < HKB; ++kb) {
            bf16x8 afn[4];
            const int last = (kb == HKB - 1);
            const int ns = last ? s + 1 : s;
            if (ns < NHALF) loadA((ns & 1) * HKB + (last ? 0 : kb + 1), afn);
            else {
#pragma unroll
                for (int mi = 0; mi < 4; ++mi) afn[mi] = af[mi];
            }
            bf16x8 bfr[8];
#pragma unroll
            for (int ni = 0; ni < 8; ++ni)
                bfr[ni] = *(const bf16x8*)(bb + (kb * 4 + quad) * 2048 + (ni * 16 + l16) * 16);
#pragma unroll
            for (int mi = 0; mi < 4; ++mi)
#pragma unroll
                for (int ni = 0; ni < 8; ++ni)
                    acc[mi][ni] = __builtin_amdgcn_mfma_f32_16x16x32_bf16(af[mi], bfr[ni], acc[mi][ni], 0, 0, 0);
#pragma unroll
            for (int mi = 0; mi < 4; ++mi) af[mi] = afn[mi];
        }

        if (h == 1) {                                // position complete: fold into running
            const int pos = s >> 1;
            const int colbase = col0s + pos * POS_W;
            const bool dg = (colbase < row0b + RPB) && (row0b < colbase + POS_W);
#pragma unroll
            for (int mi = 0; mi < 4; ++mi)
#pragma unroll
                for (int reg = 0; reg < 4; ++reg) {
                    const int r = wrow0 + mi * 16 + quad * 4 + reg;
                    float d[8];
#pragma unroll
                    for (int ni = 0; ni < 8; ++ni) d[ni] = acc[mi][ni][reg];
                    if (dg) {
#pragma unroll
                        for (int ni = 0; ni < 8; ++ni)
                            if (colbase + ni * 16 + l16 == r) d[ni] = -2.0f;
                    }
                    float m = d[0]; int ci = 0;
#pragma unroll
                    for (int ni = 1; ni < 8; ++ni) { // ties -> lower ni (lower col)
                        bool gt = d[ni] > m;
                        m  = gt ? d[ni] : m;
                        ci = gt ? ni : ci;
                    }
                    const int slot = mi * 4 + reg;
                    bool upd = m > rv[slot];         // ties -> earlier position
                    rv[slot] = upd ? m : rv[slot];
                    ri[slot] = upd ? (colbase + ci * 16 + l16) : ri[slot];
#pragma unroll
                    for (int ni = 0; ni < 8; ++ni) acc[mi][ni][reg] = 0.f;
                }
        }
        buf ^= 1;
    }

    // ---- final cross-lane reduce over the 16 col-lanes, one atomic per row ----
#pragma unroll
    for (int slot = 0; slot < 16; ++slot) {
        float v = rv[slot]; int ci = ri[slot];
#pragma unroll
        for (int m = 1; m < 16; m <<= 1) {
            float ov = __shfl_xor(v, m, 64);
            int   oi = __shfl_xor(ci, m, 64);
            bool take = (ov > v) || (ov == v && oi < ci);
            v  = take ? ov : v;
            ci = take ? oi : ci;
        }
        if (l16 == 0) {
            const int r = wrow0 + (slot >> 2) * 16 + quad * 4 + (slot & 3);
            unsigned u = __float_as_uint(v);
            u = (u & 0x80000000u) ? ~u : (u | 0x80000000u);
            unsigned long long key = ((unsigned long long)u << 32) | (unsigned)(~ci);
            atomicMax(best + r, key);
        }
    }
}

// ---------------- kernel 3: exact fp32 distance + loss ----------------
__global__ __launch_bounds__(256) void loss_kernel(const float* __restrict__ in,
                                                   const float* __restrict__ rnorm,
                                                   const unsigned long long* __restrict__ best,
                                                   float* __restrict__ out, int N) {
    __shared__ float part[4];
    const int wave = threadIdx.x >> 6, lane = threadIdx.x & 63;
    const int gw = blockIdx.x * 4 + wave;            // 1024 waves total
    float local = 0.f;
    for (int row = gw; row < N; row += 1024) {
        unsigned long long key = best[row];
        int j = (int)(~(unsigned)(key & 0xffffffffull));
        float rni = rnorm[row], rnj = rnorm[j];
        const float* pi = in + (size_t)row * D;
        const float* pj = in + (size_t)j * D;
        float s = 0.f;
#pragma unroll
        for (int c = 0; c < 6; ++c) {
            float xi = pi[lane + 64 * c] * rni;
            float xj = pj[lane + 64 * c] * rnj;
            float dvv = xi - xj + EPS;               // ||x - nn_x + eps||
            s += dvv * dvv;
        }
#pragma unroll
        for (int off = 32; off > 0; off >>= 1) s += __shfl_down(s, off, 64);
        if (lane == 0) local += -logf(sqrtf(s) + EPS);
    }
    if (lane == 0) part[wave] = local;
    __syncthreads();
    if (threadIdx.x == 0)
        atomicAdd(out, (part[0] + part[1] + part[2] + part[3]) / (float)N);
}

extern "C" void kernel_launch(void* const* d_in, const int* in_sizes, int n_in,
                              void* d_out, int out_size, void* d_ws, size_t ws_size,
                              hipStream_t stream) {
    const float* in = (const float*)d_in[0];
    float* out = (float*)d_out;
    const int N = in_sizes[0] / D;                   // 8192

    // workspace layout: rnorm (N f32) | best (N u64) | xb (N*D bf16)
    char* ws = (char*)d_ws;
    float* rnorm = (float*)ws;
    unsigned long long* best = (unsigned long long*)(ws + 64 * 1024);
    __hip_bfloat16* xb = (__hip_bfloat16*)(ws + 192 * 1024);

    prep_kernel<<<N / 4, 256, 0, stream>>>(in, rnorm, xb, best, out, N);
    maxdot_rows<<<256, 512, 0, stream>>>(xb, best);  // 16 rb x 16 cs, 1 block/CU
    loss_kernel<<<256, 256, 0, stream>>>(in, rnorm, best, out, N);
}